// Round 2
// baseline (55.190 us; speedup 1.0000x reference)
//
#include <hip/hip_runtime.h>
#include <stdint.h>

typedef unsigned long long u64;
typedef unsigned int u32;
typedef unsigned char u8;

#define Bn 32
#define Nn 320
#define WPN 5                   // u64 words per 320-bit adjacency row
#define MAXD 10
#define NH 8
#define CHS 40                  // sources per block (u64 bitset, 40 bits used)
#define NCH (Nn / CHS)          // 8 chunks per graph -> 256 blocks (1/CU)
#define TPB Nn                  // 320 threads = one node per thread
#define ESTR 12                 // emb_s row stride in floats
#define IDX_BYTES (Bn * Nn * Nn)   // 3.28 MB dist-index intermediate in d_ws

// ---------------------------------------------------------------------------
// Input-format sniffing: bool arrays may arrive as 1 byte or 4 bytes/element.
// ---------------------------------------------------------------------------
__device__ __forceinline__ bool detect_byte_mode(const u32* a32) {
    int lane = threadIdx.x & 63;
    u32 or0 = 0, or1 = 0;
    #pragma unroll
    for (int k = 0; k < 16; ++k) {
        u32 v = a32[lane + k * 64];
        or0 |= v & 0x000000FFu;
        or1 |= v & 0x0000FF00u;
    }
    bool a0 = __any(or0 != 0);
    bool a1 = __any(or1 != 0);
    return a0 && a1;
}

// ---------------------------------------------------------------------------
// Kernel 1: fused pack + node-centric multi-source BFS -> dist-index bytes.
// 256 blocks (graph x 40-source chunk) x 320 threads (one node per thread).
// Adjacency row lives in 5 VGPRs per thread (packed directly from raw input,
// no staging kernel, no adjacency LDS). Per level:
//   S_new[v] = S_old[v] | OR_{u in N(v)} S_old[u]   (u64 = 40 sources/gather)
// newly-set bits record min(level,MAXD)+1 into idx_s[src][v] (thread v owns
// column v: race-free). One __syncthreads_count per level for convergence.
// ---------------------------------------------------------------------------
__global__ __launch_bounds__(TPB) void bfs_idx(
        const u8* __restrict__ a8,
        const int* __restrict__ nn_,
        u8* __restrict__ idxg) {
    bool bytemode = detect_byte_mode((const u32*)a8);
    int b = blockIdx.x >> 3;            // graph
    int c = blockIdx.x & (NCH - 1);     // chunk
    int v = threadIdx.x;                // my node
    int nn = nn_[b];

    __shared__ u64 S[2][Nn];                       // 5120 B double-buffered
    __shared__ __align__(16) u8 idx_s[CHS][Nn];    // 12800 B

    // zero idx tile: 3200 u32 over 320 threads = exactly 10 each
    #pragma unroll
    for (int it = 0; it < 10; ++it) ((u32*)idx_s)[it * TPB + v] = 0;

    // ---- pack my adjacency row into registers (masked to nn) ----
    u64 arow[WPN] = {0, 0, 0, 0, 0};
    if (v < nn) {
        if (bytemode) {
            const uint4* p = (const uint4*)(a8 + (size_t)(b * Nn + v) * Nn);
            #pragma unroll
            for (int w = 0; w < WPN; ++w) {
                u64 bits = 0;
                #pragma unroll
                for (int q = 0; q < 4; ++q) {
                    uint4 x = p[w * 4 + q];
                    u32 n0 = ((x.x & 0x01010101u) * 0x01020408u) >> 24;
                    u32 n1 = ((x.y & 0x01010101u) * 0x01020408u) >> 24;
                    u32 n2 = ((x.z & 0x01010101u) * 0x01020408u) >> 24;
                    u32 n3 = ((x.w & 0x01010101u) * 0x01020408u) >> 24;
                    u64 nib = (u64)((n0 & 0xF) | ((n1 & 0xF) << 4) |
                                    ((n2 & 0xF) << 8) | ((n3 & 0xF) << 12));
                    bits |= nib << (q * 16);
                }
                arow[w] = bits;
            }
        } else {
            const uint4* p = (const uint4*)(((const u32*)a8) + (size_t)(b * Nn + v) * Nn);
            #pragma unroll
            for (int w = 0; w < WPN; ++w) {
                u64 bits = 0;
                #pragma unroll
                for (int q = 0; q < 16; ++q) {
                    uint4 x = p[w * 16 + q];
                    u64 nib = (u64)((x.x != 0u) | ((x.y != 0u) << 1) |
                                    ((x.z != 0u) << 2) | ((x.w != 0u) << 3));
                    bits |= nib << (q * 4);
                }
                arow[w] = bits;
            }
        }
        #pragma unroll
        for (int w = 0; w < WPN; ++w) {
            int cc = nn - w * 64;
            u64 msk = (cc >= 64) ? ~0ull : ((cc <= 0) ? 0ull : ((1ull << cc) - 1ull));
            arow[w] &= msk;
        }
    }

    int base = c * CHS;
    u64 init = 0;
    if (v >= base && v < base + CHS && v < nn) init = 1ull << (v - base);
    S[0][v] = init;
    int vs = nn - base; if (vs > CHS) vs = CHS; if (vs < 0) vs = 0;
    u64 full = (1ull << vs) - 1ull;     // vs <= 40 < 64, no overflow
    __syncthreads();
    if (init) idx_s[v - base][v] = 1;   // dist 0 -> emb idx 1

    int p = 0;
    for (int level = 1; level <= Nn; ++level) {
        const u64* Sp = S[p];
        u64 mo = Sp[v];
        u64 acc = mo;
        if (mo != full) {               // saturation skip
            #pragma unroll
            for (int w = 0; w < WPN; ++w) {
                u64 m = arow[w];
                int ub = w * 64;
                while (m) {
                    int u0 = ub + (int)__builtin_ctzll(m); m &= m - 1;
                    if (m) {            // pair-unrolled: 2 gathers in flight
                        int u1 = ub + (int)__builtin_ctzll(m); m &= m - 1;
                        acc |= Sp[u0] | Sp[u1];
                    } else {
                        acc |= Sp[u0];
                    }
                }
            }
        }
        u64 nw = acc & ~mo;
        S[p ^ 1][v] = acc;
        if (nw) {
            u8 val = (u8)((level < MAXD ? level : MAXD) + 1);
            u64 m2 = nw;
            while (m2) {
                int s2 = (int)__builtin_ctzll(m2); m2 &= m2 - 1;
                idx_s[s2][v] = val;
            }
        }
        if (__syncthreads_count(nw != 0) == 0) break;   // barrier + converge
        p ^= 1;
    }

    // ---- writeout: 12800 B = 800 uint4, coalesced ----
    {
        uint4* dst = (uint4*)(idxg + (size_t)b * (Nn * Nn) + (size_t)base * Nn);
        const uint4* src = (const uint4*)idx_s;
        #pragma unroll
        for (int it = 0; it < 3; ++it) {
            int i = it * TPB + v;
            if (i < (CHS * Nn) / 16) dst[i] = src[i];
        }
    }
}

// ---------------------------------------------------------------------------
// Kernel 2: pure bandwidth gather-write. 2560 blocks x 256 threads x 10 f4.
// Lane-contiguous float4 stores; idx byte shared by 2 lanes; emb in LDS.
// ---------------------------------------------------------------------------
#define K3_TPB 256
#define K3_PER 10
#define K3_BLOCKS ((Bn * Nn * Nn * (NH / 4)) / (K3_TPB * K3_PER))   // 2560

__global__ __launch_bounds__(K3_TPB) void emb_write(
        const u8* __restrict__ idxg,
        const float* __restrict__ emb,
        float4* __restrict__ out4) {
    __shared__ __align__(16) float emb_s[(MAXD + 2) * ESTR];   // 576 B
    int t = threadIdx.x;
    if (t < (MAXD + 2) * NH) emb_s[(t >> 3) * ESTR + (t & 7)] = emb[t];
    __syncthreads();
    size_t base = (size_t)blockIdx.x * (K3_TPB * K3_PER);
    #pragma unroll
    for (int i = 0; i < K3_PER; ++i) {
        size_t G = base + (size_t)(i * K3_TPB + t);
        int e = idxg[G >> 1];
        out4[G] = *(const float4*)(emb_s + e * ESTR + ((t & 1) << 2));
    }
}

extern "C" void kernel_launch(void* const* d_in, const int* in_sizes, int n_in,
                              void* d_out, int out_size, void* d_ws, size_t ws_size,
                              hipStream_t stream) {
    const u8*    adj = (const u8*)d_in[0];
    const int*   nn  = (const int*)d_in[1];
    const float* emb = (const float*)d_in[2];

    u8* idxg = (u8*)d_ws;   // 3.28 MB dist-index intermediate

    bfs_idx<<<Bn * NCH, TPB, 0, stream>>>(adj, nn, idxg);
    emb_write<<<K3_BLOCKS, K3_TPB, 0, stream>>>(idxg, emb, (float4*)d_out);
}